// Round 6
// baseline (784.848 us; speedup 1.0000x reference)
//
#include <hip/hip_runtime.h>

#define N_NODES 200000
#define N_EDGES 6400000

constexpr int BSHIFT = 9;                      // 512 nodes per bucket
constexpr int NBUCK  = (N_NODES + 511) / 512;  // 391
constexpr int CHUNK  = 16384;
constexpr int NCHUNK = (N_EDGES + CHUNK - 1) / CHUNK;  // 391
constexpr int MAXBUCK = 18432;                 // lambda=16384, +16 sigma
constexpr int NSEG   = 4;                      // src-range segments (q = src/50000)
constexpr int SEGSTRIDE = 2052;                // 2048 bins + end sentinel + pad

typedef float v4f __attribute__((ext_vector_type(4)));

// ---- edge index load helper: handles int32 or int64 storage ----
__device__ __forceinline__ int ld_edge(const void* ei, int is64, int idx) {
    return is64 ? (int)((const long long*)ei)[idx] : ((const int*)ei)[idx];
}

__global__ void k_zero(int* __restrict__ p, int n) {
    int i = blockIdx.x * blockDim.x + threadIdx.x;
    if (i < n) p[i] = 0;
}

// int64 little-endian values < 2^31  =>  every odd u32 slot is 0
__global__ void k_detect(const unsigned int* __restrict__ ei, int* __restrict__ flag) {
    __shared__ int nz;
    if (threadIdx.x == 0) nz = 0;
    __syncthreads();
    if (ei[2 * threadIdx.x + 1] != 0u) atomicOr(&nz, 1);
    __syncthreads();
    if (threadIdx.x == 0) *flag = nz ? 0 : 1;
}

// bucket histogram: LDS-accumulated, one global atomic per bucket per block
__global__ void k_hist(const void* __restrict__ ei, const int* __restrict__ flag,
                       int* __restrict__ bucketCnt) {
    __shared__ int h[NBUCK];
    for (int i = threadIdx.x; i < NBUCK; i += 256) h[i] = 0;
    __syncthreads();
    const int is64 = *flag;
    int stride = gridDim.x * blockDim.x;
    for (int e = blockIdx.x * 256 + threadIdx.x; e < N_EDGES; e += stride) {
        int d = ld_edge(ei, is64, N_EDGES + e);
        atomicAdd(&h[d >> BSHIFT], 1);
    }
    __syncthreads();
    for (int i = threadIdx.x; i < NBUCK; i += 256)
        if (h[i]) atomicAdd(&bucketCnt[i], h[i]);
}

// single-block scan of 391 bucket counts -> exclusive bases + cursors
__global__ void k_scan_buckets(const int* __restrict__ bucketCnt,
                               int* __restrict__ bucketBase,
                               int* __restrict__ bucketCursor) {
    __shared__ int sc[512];
    int t = threadIdx.x;
    sc[t]       = (t < NBUCK)       ? bucketCnt[t]       : 0;
    sc[t + 256] = (t + 256 < NBUCK) ? bucketCnt[t + 256] : 0;
    __syncthreads();
    for (int off = 1; off < 512; off <<= 1) {
        int a0 = (t >= off) ? sc[t - off] : 0;
        int a1 = sc[t + 256 - off];
        __syncthreads();
        sc[t] += a0; sc[t + 256] += a1;
        __syncthreads();
    }
    for (int i = t; i < NBUCK; i += 256) {
        int excl = sc[i] - bucketCnt[i];
        bucketBase[i] = excl;
        bucketCursor[i] = excl;
    }
    if (t == 0) bucketBase[NBUCK] = N_EDGES;
}

// level-1: bin a 16K-edge chunk by bucket in LDS, write contiguous runs
__global__ void __launch_bounds__(256)
k_binscatter(const void* __restrict__ ei, const int* __restrict__ flag,
             int* __restrict__ bucketCursor, unsigned int* __restrict__ bin) {
    __shared__ int hist[NBUCK];
    __shared__ int pref[NBUCK + 1];
    __shared__ int cur[NBUCK];
    __shared__ int gb[NBUCK];
    __shared__ int sc[512];
    __shared__ unsigned int stage[CHUNK];
    const int is64 = *flag;
    int b = blockIdx.x, t = threadIdx.x;
    int e0 = b * CHUNK;
    int n = min(CHUNK, N_EDGES - e0);
    for (int i = t; i < NBUCK; i += 256) hist[i] = 0;
    __syncthreads();
    for (int i = t; i < n; i += 256) {
        int d = ld_edge(ei, is64, N_EDGES + e0 + i);
        atomicAdd(&hist[d >> BSHIFT], 1);
    }
    __syncthreads();
    sc[t]       = (t < NBUCK)       ? hist[t]       : 0;
    sc[t + 256] = (t + 256 < NBUCK) ? hist[t + 256] : 0;
    __syncthreads();
    for (int off = 1; off < 512; off <<= 1) {
        int a0 = (t >= off) ? sc[t - off] : 0;
        int a1 = sc[t + 256 - off];
        __syncthreads();
        sc[t] += a0; sc[t + 256] += a1;
        __syncthreads();
    }
    for (int i = t; i < NBUCK; i += 256) {
        int excl = sc[i] - hist[i];
        pref[i] = excl;
        cur[i] = excl;
    }
    if (t == 0) pref[NBUCK] = n;
    __syncthreads();
    for (int i = t; i < n; i += 256) {
        int s = ld_edge(ei, is64, e0 + i);
        int d = ld_edge(ei, is64, N_EDGES + e0 + i);
        int bk = d >> BSHIFT;
        int p = atomicAdd(&cur[bk], 1);
        stage[p] = ((unsigned int)(d & 511) << 18) | (unsigned int)s;
    }
    __syncthreads();
    for (int i = t; i < NBUCK; i += 256) {
        int c = hist[i];
        gb[i] = c ? atomicAdd(&bucketCursor[i], c) : 0;
    }
    __syncthreads();
    for (int p = t; p < n; p += 256) {
        int lo = 0, hi = NBUCK;
        while (hi - lo > 1) {
            int mid = (lo + hi) >> 1;
            if (pref[mid] <= p) lo = mid; else hi = mid;
        }
        bin[gb[lo] + (p - pref[lo])] = stage[p];
    }
}

// level-2: one block per bucket. Counting-sort the bucket's edges by key
// (q<<9)|local_dst (q = src/50000), emit per-(q,dst) u16 rowptr + dinv.
__global__ void __launch_bounds__(256)
k_bucketsort(const int* __restrict__ bucketBase, unsigned int* __restrict__ bin,
             float* __restrict__ dinv, unsigned short* __restrict__ seg16) {
    __shared__ int cnt[2048];
    __shared__ int cur[2048];
    __shared__ int tsum[256];
    __shared__ unsigned int payload[MAXBUCK];
    int b = blockIdx.x, t = threadIdx.x;
    int base = bucketBase[b], end = bucketBase[b + 1];
    int n = end - base;
    for (int i = t; i < 2048; i += 256) cnt[i] = 0;
    __syncthreads();
    // pass A: histogram over 2048 (q, local_dst) bins
    for (int i = t; i < n; i += 256) {
        unsigned int u = bin[base + i];
        int src = (int)(u & 0x3FFFFu);
        int key = ((src / 50000) << 9) | (int)(u >> 18);
        atomicAdd(&cnt[key], 1);
    }
    __syncthreads();
    // scan 2048: serial-8 per thread + Hillis-Steele over 256 thread sums
    int b0 = t * 8;
    int s = 0;
#pragma unroll
    for (int j = 0; j < 8; ++j) s += cnt[b0 + j];
    tsum[t] = s;
    __syncthreads();
    int v = s;
    for (int off = 1; off < 256; off <<= 1) {
        int add = (t >= off) ? tsum[t - off] : 0;
        __syncthreads();
        tsum[t] += add;
        __syncthreads();
    }
    int run = tsum[t] - v;  // exclusive prefix of this thread's chunk
#pragma unroll
    for (int j = 0; j < 8; ++j) { cur[b0 + j] = run; run += cnt[b0 + j]; }
    __syncthreads();
    // write u16 relative rowptr (before scatter mutates cur) + sentinel + dinv
    for (int i = t; i < 2048; i += 256)
        seg16[b * SEGSTRIDE + i] = (unsigned short)cur[i];
    if (t == 0) seg16[b * SEGSTRIDE + 2048] = (unsigned short)n;
    int node0 = b << BSHIFT;
    for (int d = t; d < 512; d += 256) {
        int node = node0 + d;
        if (node < N_NODES) {
            int deg = cnt[d] + cnt[512 + d] + cnt[1024 + d] + cnt[1536 + d];
            dinv[node] = rsqrtf((float)deg + 1.0f);
        }
    }
    __syncthreads();
    // pass B: scatter into payload by final position
    for (int i = t; i < n; i += 256) {
        unsigned int u = bin[base + i];
        int src = (int)(u & 0x3FFFFu);
        int key = ((src / 50000) << 9) | (int)(u >> 18);
        int p = atomicAdd(&cur[key], 1);
        if (p < MAXBUCK) payload[p] = u;
    }
    __syncthreads();
    // coalesced in-place write-back (sorted by (q, local_dst))
    for (int i = t; i < n; i += 256) bin[base + i] = payload[i];
}

// hs = dinv[i] * (x @ W), padded to stride 16 (one 64B line per row).
template <int FIN, int FOUT, int SIN>
__global__ void k_xw(const float* xin, const float* __restrict__ W,
                     const float* __restrict__ dinv, float* hs) {
    __shared__ float sW[FIN * FOUT];
    int t = threadIdx.x;
    if (t < FIN * FOUT) sW[t] = W[t];
    __syncthreads();
    int i = blockIdx.x * 256 + t;
    if (i >= N_NODES) return;
    float xi[FIN];
#pragma unroll
    for (int k = 0; k < FIN; ++k) xi[k] = xin[i * SIN + k];
    float di = dinv[i];
    float o[FOUT];
#pragma unroll
    for (int j = 0; j < FOUT; ++j) {
        float acc = 0.f;
#pragma unroll
        for (int k = 0; k < FIN; ++k) acc += xi[k] * sW[k * FOUT + j];
        o[j] = di * acc;
    }
#pragma unroll
    for (int j = 0; j < FOUT; ++j) hs[i * 16 + j] = o[j];
}

// Fused boundary kernel: x' = relu(dinv*(accG + hs_prev) + biasPrev);
// hs_next = dinv * (x' @ Wnext) -> B. Also re-zeros accG.
template <int FIN, int FOUT>
__global__ void k_fx(float* __restrict__ B, float* __restrict__ accG,
                     const float* __restrict__ dinv,
                     const float* __restrict__ biasPrev,
                     const float* __restrict__ Wnext) {
    __shared__ float sW[FIN * FOUT];
    __shared__ float sb[FIN];
    int t = threadIdx.x;
    if (t < FIN * FOUT) sW[t] = Wnext[t];
    if (t < FIN) sb[t] = biasPrev[t];
    __syncthreads();
    int i = blockIdx.x * 256 + t;
    if (i >= N_NODES) return;
    float di = dinv[i];
    float xi[FIN];
#pragma unroll
    for (int k = 0; k < FIN; ++k) {
        float v = di * (accG[i * 16 + k] + B[i * 16 + k]) + sb[k];
        xi[k] = fmaxf(v, 0.f);
    }
#pragma unroll
    for (int c = 0; c < 16; ++c) accG[i * 16 + c] = 0.f;
    float o[FOUT];
#pragma unroll
    for (int j = 0; j < FOUT; ++j) {
        float acc = 0.f;
#pragma unroll
        for (int k = 0; k < FIN; ++k) acc += xi[k] * sW[k * FOUT + j];
        o[j] = di * acc;
    }
#pragma unroll
    for (int j = 0; j < FOUT; ++j) B[i * 16 + j] = o[j];
}

// One block per (bucket, quarter, q); 128 groups x 4 lanes, float4 per lane.
// Group g owns ONE (q,dst) contiguous edge run; unroll-4 keeps 8 independent
// loads in flight per lane; 2 float4 accumulator chains; one coalesced
// global_atomic_add_f32 x4 per lane at the end. q = blk&3 pins each q's
// 3.2 MB hs window to one XCD pair (L2-resident).
__global__ void __launch_bounds__(512)
k_agg(const int* __restrict__ bucketBase, const unsigned short* __restrict__ seg16,
      const unsigned int* __restrict__ bin, const float* __restrict__ hs,
      float* __restrict__ accG) {
    __shared__ unsigned short s_sr[132];
    int blk = blockIdx.x;
    int q = blk & 3;
    int Q = (blk >> 2) & 3;
    int b = blk >> 4;
    int t = threadIdx.x;
    int base = bucketBase[b];
    const unsigned short* sr = seg16 + b * SEGSTRIDE + (q << 9) + (Q << 7);
    if (t < 129) s_sr[t] = sr[t];
    __syncthreads();
    int g = t >> 2, l = t & 3;
    int e0 = base + (int)s_sr[g];
    int e1 = base + (int)s_sr[g + 1];
    const v4f* hs4 = (const v4f*)hs;
    v4f a0 = {0.f, 0.f, 0.f, 0.f}, a1 = {0.f, 0.f, 0.f, 0.f};
    int e = e0;
    for (; e + 3 < e1; e += 4) {
        unsigned int u0 = bin[e];
        unsigned int u1 = bin[e + 1];
        unsigned int u2 = bin[e + 2];
        unsigned int u3 = bin[e + 3];
        v4f v0 = hs4[((u0 & 0x3FFFFu) << 2) + l];
        v4f v1 = hs4[((u1 & 0x3FFFFu) << 2) + l];
        v4f v2 = hs4[((u2 & 0x3FFFFu) << 2) + l];
        v4f v3 = hs4[((u3 & 0x3FFFFu) << 2) + l];
        a0 += v0; a1 += v1; a0 += v2; a1 += v3;
    }
    for (; e < e1; ++e) {
        unsigned int u = bin[e];
        a0 += hs4[((u & 0x3FFFFu) << 2) + l];
    }
    a0 += a1;
    int node = (b << BSHIFT) + (Q << 7) + g;
    if (node < N_NODES) {
        float* p = &accG[(node << 4) + (l << 2)];
        unsafeAtomicAdd(p + 0, a0.x);
        unsafeAtomicAdd(p + 1, a0.y);
        unsafeAtomicAdd(p + 2, a0.z);
        unsafeAtomicAdd(p + 3, a0.w);
    }
}

// out = dinv*(accG + hs_self) + bias, in place (accG aliases d_out).
template <int F, bool RELU>
__global__ void k_finish(float* __restrict__ B, float* __restrict__ accG,
                         const float* __restrict__ dinv,
                         const float* __restrict__ bias, float* __restrict__ out) {
    int i = blockIdx.x * blockDim.x + threadIdx.x;
    if (i >= N_NODES * 16) return;
    int node = i >> 4, ff = i & 15;
    float di = dinv[node];
    if (ff < F) {
        float r = di * (accG[i] + B[i]) + bias[ff];
        if (RELU) r = fmaxf(r, 0.f);
        out[node * 16 + ff] = r;
    }
}

extern "C" void kernel_launch(void* const* d_in, const int* in_sizes, int n_in,
                              void* d_out, int out_size, void* d_ws, size_t ws_size,
                              hipStream_t stream) {
    const float* x  = (const float*)d_in[0];
    const void*  ei = d_in[1];
    const float* W1 = (const float*)d_in[2];
    const float* b1 = (const float*)d_in[3];
    const float* W2 = (const float*)d_in[4];
    const float* b2 = (const float*)d_in[5];
    const float* W3 = (const float*)d_in[6];
    const float* b3 = (const float*)d_in[7];
    float* out = (float*)d_out;

    char* w = (char*)d_ws;
    int*   bucketCnt    = (int*)(w + 0);        //    2048 B (512 ints, zeroed)
    int*   bucketBase   = (int*)(w + 2048);     //    2048 B
    int*   bucketCursor = (int*)(w + 4096);     //    2048 B
    int*   flag         = (int*)(w + 6144);     //      64 B
    float* dinv         = (float*)(w + 6208);   //  800000 B
    unsigned short* seg16 = (unsigned short*)(w + 806208); // 391*2052*2 = 1604664 B
    unsigned int* bin   = (unsigned int*)(w + 2410880);    // 25600000 B
    float* B            = (float*)(w + 28010880);          // 12800000 B (N*16)
    float* accG         = out;                  // d_out doubles as accumulator
    // total ws use ~40.8 MB

    // ---- zero accumulator (d_out) + build (q,dst)-sorted bucketed edges ----
    k_zero<<<12500, 256, 0, stream>>>((int*)accG, N_NODES * 16);
    k_zero<<<2, 256, 0, stream>>>(bucketCnt, 512);
    k_detect<<<1, 256, 0, stream>>>((const unsigned int*)ei, flag);
    k_hist<<<1024, 256, 0, stream>>>(ei, flag, bucketCnt);
    k_scan_buckets<<<1, 256, 0, stream>>>(bucketCnt, bucketBase, bucketCursor);
    k_binscatter<<<NCHUNK, 256, 0, stream>>>(ei, flag, bucketCursor, bin);
    k_bucketsort<<<NBUCK, 256, 0, stream>>>(bucketBase, bin, dinv, seg16);

    // ---- layer 1 ----
    k_xw<11, 11, 11><<<782, 256, 0, stream>>>(x, W1, dinv, B);
    k_agg<<<NBUCK * 16, 512, 0, stream>>>(bucketBase, seg16, bin, B, accG);
    // ---- boundary 1: finish L1 + xw L2 (re-zeros accG) ----
    k_fx<11, 11><<<782, 256, 0, stream>>>(B, accG, dinv, b1, W2);
    // ---- layer 2 ----
    k_agg<<<NBUCK * 16, 512, 0, stream>>>(bucketBase, seg16, bin, B, accG);
    // ---- boundary 2: finish L2 + xw L3 (re-zeros accG) ----
    k_fx<11, 16><<<782, 256, 0, stream>>>(B, accG, dinv, b2, W3);
    // ---- layer 3 ----
    k_agg<<<NBUCK * 16, 512, 0, stream>>>(bucketBase, seg16, bin, B, accG);
    k_finish<16, false><<<12500, 256, 0, stream>>>(B, accG, dinv, b3, out);
}